// Round 10
// baseline (197.451 us; speedup 1.0000x reference)
//
#include <hip/hip_runtime.h>
#include <hip/hip_bf16.h>

#define IN_EPS 1e-5f

typedef __attribute__((ext_vector_type(8))) short short8;
typedef __attribute__((ext_vector_type(4))) float f32x4;

__device__ __forceinline__ short f2bf(float f) {
  __hip_bfloat16 h = (__hip_bfloat16)f;   // lowers to v_cvt_pk_bf16_f32
  return *(short*)&h;
}
__device__ __forceinline__ float bf2f(short s) {
  union { unsigned u; float f; } x;
  x.u = ((unsigned)(unsigned short)s) << 16;
  return x.f;
}

__device__ __forceinline__ void glds16(const void* g, void* l) {
  typedef const __attribute__((address_space(1))) void gconst_t;
  typedef __attribute__((address_space(3))) void lds_t;
  __builtin_amdgcn_global_load_lds((gconst_t*)g, (lds_t*)l, 16, 0, 0);
}

// ---------------------------------------------------------------------------
// Weight conversion: f32 [O][C][3][3] -> bf16 swizzled panel image.
// Panel p = mblk*36 + cb*9 + tap holds [o_local 128][c_local 64], elem at
//   (p<<13) + (ol<<6) + (cl ^ ((ol&7)<<3))
// ---------------------------------------------------------------------------
__global__ void wconv_k(const float* __restrict__ src, short* __restrict__ dst,
                        int O) {
  int idx = blockIdx.x * 256 + threadIdx.x;
  if (idx >= O * 2304) return;
  int o = idx / 2304;
  int r = idx - o * 2304;
  int c = r / 9;
  int k = r - c * 9;
  int mblk = o >> 7, ol = o & 127, cb = c >> 6, cl = c & 63;
  dst[(((size_t)(mblk * 36 + cb * 9 + k)) << 13) + (ol << 6) + (cl ^ ((ol & 7) << 3))]
      = f2bf(src[idx]);
}

// ---------------------------------------------------------------------------
// Adaptive Gaussian kernel: kern[b][k][h][w] = exp(-0.5 * sum_c dg^2)
// lane == image col; neighbors via shfl; no barriers in the channel loop.
// ---------------------------------------------------------------------------
__global__ __launch_bounds__(256) void kern_k(const float* __restrict__ g,
                                              float* __restrict__ kern) {
  int h = blockIdx.x, b = blockIdx.y;
  int t = threadIdx.x, w = t & 63, cg = t >> 6;
  float acc[9];
#pragma unroll
  for (int k = 0; k < 9; ++k) acc[k] = 0.f;
  const float* base = g + (((size_t)b * 256 + (cg << 6)) << 12) + (h << 6) + w;
#pragma unroll 4
  for (int cc = 0; cc < 64; ++cc) {
    const float* gp = base + ((size_t)cc << 12);
    float mid = gp[0];
    float top = (h > 0) ? gp[-64] : 0.f;
    float bot = (h < 63) ? gp[64] : 0.f;
    float rows[3] = {top, mid, bot};
#pragma unroll
    for (int i = 0; i < 3; ++i) {
      float v = rows[i];
      float l = __shfl_up(v, 1);
      float r = __shfl_down(v, 1);
      if (w == 0) l = 0.f;
      if (w == 63) r = 0.f;
      float dl = l - mid, dm = v - mid, dr = r - mid;
      acc[i * 3 + 0] += dl * dl;
      acc[i * 3 + 1] += dm * dm;
      acc[i * 3 + 2] += dr * dr;
    }
  }
  __shared__ float red[4][9][64];
#pragma unroll
  for (int k = 0; k < 9; ++k) red[cg][k][w] = acc[k];
  __syncthreads();
  for (int idx = t; idx < 576; idx += 256) {
    int k = idx >> 6, w2 = idx & 63;
    float s = red[0][k][w2] + red[1][k][w2] + red[2][k][w2] + red[3][k][w2];
    kern[(((size_t)b * 9 + k) << 12) + (h << 6) + w2] = expf(-0.5f * s);
  }
}

// ---------------------------------------------------------------------------
// Implicit-GEMM conv, tap-reuse, 256 thr / 4 waves (2Mx2N), wave tile 64x64
// (4mf x 4nf: 8 fragment-reads per 16 MFMA -> LDS-read : MFMA balanced).
// BM=128, BN=128 (2 image rows). K = ncb c-blocks x 9 taps.
// A: DOUBLE-BUFFERED LDS via global_load_lds from pre-swizzled panels;
//    next panel issued BEFORE compute -> DMA flies under MFMA; the single
//    end-of-step barrier (vmcnt drain) lands it. 1 barrier/interior step.
// B: halo [4 rows][64 cols][64 ch] staged serially at c-block boundaries
//    (no cross-compute register holds -- spill safety).
// GEMM1 (USE_KERN): per-mf mini-partials p0..p3 (scoped), then
//   acc += kern[tap,px] * p (f32 fma epilogue).
// GEMM2 (USE_NORM, KSPLIT): norm+relu fused into staging; K split across
//   blockIdx.y; partials to outA / outB.
// ---------------------------------------------------------------------------
template <int MTOT, bool USE_KERN, bool USE_NORM, bool KSPLIT>
__global__ __launch_bounds__(256, 2) void gemm_conv(
    const short* __restrict__ Wimg, const float* __restrict__ X,
    const float* __restrict__ Kf, const float* __restrict__ MRin,
    float* __restrict__ outA, float* __restrict__ outB) {
  __shared__ short ldsA[2][8192];  // [o 128][c 64] swizzled, dbuf, 32KB
  __shared__ short ldsB[16384];    // [r 4][col 64][c 64] swizzled, 32KB
  __shared__ short ldsS[512];      // side halo cols (-1,64): zeros, 1KB
  __shared__ short klds[USE_KERN ? 1152 : 1];  // kern bf16 [9][128]

  const int t = threadIdx.x;
  const int nblk = blockIdx.x, b = blockIdx.z;
  const int mblk = KSPLIT ? 0 : blockIdx.y;
  const int cb0 = KSPLIT ? (int)blockIdx.y * 2 : 0;
  const int ncb = KSPLIT ? 2 : 4;
  float* __restrict__ outp = (KSPLIT && blockIdx.y) ? outB : outA;
  const int h0 = nblk * 2;
  const int lane = t & 63, wid = t >> 6;
  const int wr = wid >> 1, wc = wid & 1;
  const int fr = lane & 15, kg = (lane >> 4) << 3;
  const int scol = t & 63, c16 = (t >> 6) << 4;   // B staging: col, 16-ch base

  f32x4 acc[4][4];
#pragma unroll
  for (int i = 0; i < 4; ++i)
#pragma unroll
    for (int j = 0; j < 4; ++j) acc[i][j] = {0.f, 0.f, 0.f, 0.f};

  auto stageA = [&](int pan, int buf) {
    const short* src = Wimg + ((size_t)(mblk * 36 + cb0 * 9 + pan) << 13);
#pragma unroll
    for (int i = 0; i < 4; ++i)
      glds16(src + (((i << 8) + t) << 3),
             &ldsA[buf][((i << 8) + (wid << 6)) << 3]);
  };
  auto stageB = [&](int cbrel) {
    int c0 = ((cb0 + cbrel) << 6) + c16;
    float2 mr[16];
    if (USE_NORM) {
#pragma unroll
      for (int i = 0; i < 16; ++i)
        mr[i] = ((const float2*)MRin)[b * 256 + c0 + i];
    }
#pragma unroll
    for (int r = 0; r < 4; ++r) {
      int hr = h0 - 1 + r;
      bool okr = (unsigned)hr < 64u;
      const float* src = X + (((size_t)b * 256 + c0) << 12) + (hr << 6) + scol;
      short8 pk0, pk1;
#pragma unroll
      for (int i = 0; i < 8; ++i) {
        float x = okr ? src[(size_t)i << 12] : 0.f;
        float y = okr ? src[(size_t)(i + 8) << 12] : 0.f;
        if (USE_NORM) {
          x = fmaxf((x - mr[i].x) * mr[i].y, 0.f);
          y = fmaxf((y - mr[i + 8].x) * mr[i + 8].y, 0.f);
        }
        pk0[i] = f2bf(x);
        pk1[i] = f2bf(y);
      }
      int base = ((r << 6) + scol) << 6;
      *(short8*)&ldsB[base + (c16 ^ ((scol & 7) << 3))] = pk0;
      *(short8*)&ldsB[base + ((c16 + 8) ^ ((scol & 7) << 3))] = pk1;
    }
  };
  auto computeTap = [&](int tap, int buf) {
    const int di = tap / 3 - 1, dj = tap % 3 - 1;
    const int rw = wc + di + 1;    // halo row for this wave (uniform)
    float kq0, kq1, kq2, kq3;
    if (USE_KERN) {
      kq0 = bf2f(klds[tap * 128 + (wc << 6) + fr]);
      kq1 = bf2f(klds[tap * 128 + (wc << 6) + 16 + fr]);
      kq2 = bf2f(klds[tap * 128 + (wc << 6) + 32 + fr]);
      kq3 = bf2f(klds[tap * 128 + (wc << 6) + 48 + fr]);
    }
    short8 Bf[2][4];
#pragma unroll
    for (int ks = 0; ks < 2; ++ks) {
      int kb = (ks << 5) + kg;
#pragma unroll
      for (int nf = 0; nf < 4; ++nf) {
        int wcol = (nf << 4) + fr + dj;
        int kbs = kb ^ ((wcol & 7) << 3);
        const short* pm = &ldsB[(((rw << 6) + wcol) << 6) + kbs];
        const short* ps = &ldsS[(((rw << 1) + (wcol == 64)) << 6) + kbs];
        Bf[ks][nf] = *(const short8*)(((unsigned)wcol < 64u) ? pm : ps);
      }
    }
#pragma unroll
    for (int mf = 0; mf < 4; ++mf) {
      int rr = (wr << 6) + (mf << 4) + fr;
      int xr = (rr & 7) << 3;
      short8 A0 = *(const short8*)&ldsA[buf][(rr << 6) + (kg ^ xr)];
      short8 A1 = *(const short8*)&ldsA[buf][(rr << 6) + ((32 + kg) ^ xr)];
      __builtin_amdgcn_s_setprio(1);
      if (USE_KERN) {
        f32x4 p0 = {0.f, 0.f, 0.f, 0.f}, p1 = {0.f, 0.f, 0.f, 0.f};
        f32x4 p2 = {0.f, 0.f, 0.f, 0.f}, p3 = {0.f, 0.f, 0.f, 0.f};
        p0 = __builtin_amdgcn_mfma_f32_16x16x32_bf16(A0, Bf[0][0], p0, 0, 0, 0);
        p1 = __builtin_amdgcn_mfma_f32_16x16x32_bf16(A0, Bf[0][1], p1, 0, 0, 0);
        p2 = __builtin_amdgcn_mfma_f32_16x16x32_bf16(A0, Bf[0][2], p2, 0, 0, 0);
        p3 = __builtin_amdgcn_mfma_f32_16x16x32_bf16(A0, Bf[0][3], p3, 0, 0, 0);
        p0 = __builtin_amdgcn_mfma_f32_16x16x32_bf16(A1, Bf[1][0], p0, 0, 0, 0);
        p1 = __builtin_amdgcn_mfma_f32_16x16x32_bf16(A1, Bf[1][1], p1, 0, 0, 0);
        p2 = __builtin_amdgcn_mfma_f32_16x16x32_bf16(A1, Bf[1][2], p2, 0, 0, 0);
        p3 = __builtin_amdgcn_mfma_f32_16x16x32_bf16(A1, Bf[1][3], p3, 0, 0, 0);
        __builtin_amdgcn_s_setprio(0);
#pragma unroll
        for (int j = 0; j < 4; ++j) {
          acc[mf][0][j] += kq0 * p0[j];
          acc[mf][1][j] += kq1 * p1[j];
          acc[mf][2][j] += kq2 * p2[j];
          acc[mf][3][j] += kq3 * p3[j];
        }
      } else {
        acc[mf][0] = __builtin_amdgcn_mfma_f32_16x16x32_bf16(A0, Bf[0][0], acc[mf][0], 0, 0, 0);
        acc[mf][1] = __builtin_amdgcn_mfma_f32_16x16x32_bf16(A0, Bf[0][1], acc[mf][1], 0, 0, 0);
        acc[mf][2] = __builtin_amdgcn_mfma_f32_16x16x32_bf16(A0, Bf[0][2], acc[mf][2], 0, 0, 0);
        acc[mf][3] = __builtin_amdgcn_mfma_f32_16x16x32_bf16(A0, Bf[0][3], acc[mf][3], 0, 0, 0);
        acc[mf][0] = __builtin_amdgcn_mfma_f32_16x16x32_bf16(A1, Bf[1][0], acc[mf][0], 0, 0, 0);
        acc[mf][1] = __builtin_amdgcn_mfma_f32_16x16x32_bf16(A1, Bf[1][1], acc[mf][1], 0, 0, 0);
        acc[mf][2] = __builtin_amdgcn_mfma_f32_16x16x32_bf16(A1, Bf[1][2], acc[mf][2], 0, 0, 0);
        acc[mf][3] = __builtin_amdgcn_mfma_f32_16x16x32_bf16(A1, Bf[1][3], acc[mf][3], 0, 0, 0);
        __builtin_amdgcn_s_setprio(0);
      }
    }
  };

  // ---- prologue ----
  if (t < 64) {
    short8 z = {0, 0, 0, 0, 0, 0, 0, 0};
    *(short8*)&ldsS[t << 3] = z;
  }
  if (USE_KERN) {
    for (int idx = t; idx < 1152; idx += 256) {
      int tap = idx >> 7, px = idx & 127;
      klds[idx] = f2bf(Kf[(((size_t)b * 9 + tap) << 12) +
                          ((h0 + (px >> 6)) << 6) + (px & 63)]);
    }
  }
  stageA(0, 0);
  stageB(0);
  __syncthreads();   // drains glds vmcnt; publishes B / klds / ldsS

  // ---- main loop: ncb c-blocks x 9 taps; 1 barrier per interior step ----
  const int nt = ncb * 9;
  int tap = 0, cbrel = 0;
  for (int pan = 0; pan < nt; ++pan) {
    int buf = pan & 1;
    bool more = (pan + 1) < nt;
    if (more) stageA(pan + 1, buf ^ 1);   // async DMA into idle buffer
    computeTap(tap, buf);
    if (more) {
      __syncthreads();                    // A(pan+1) landed; B readers done
      if (tap == 8) {
        stageB(cbrel + 1);                // serial boundary staging
        __syncthreads();                  // publish new B
      }
    }
    if (++tap == 9) { tap = 0; ++cbrel; }
  }

  // ---- epilogue ----
  const int row4 = (lane >> 4) << 2;
#pragma unroll
  for (int mf = 0; mf < 4; ++mf) {
    int o = (mblk << 7) + (wr << 6) + (mf << 4) + row4;
    size_t ob = (((size_t)b * MTOT + o) << 12) + (nblk << 7) + (wc << 6) + fr;
#pragma unroll
    for (int nf = 0; nf < 4; ++nf) {
      f32x4 v = acc[mf][nf];
      size_t oo = ob + (nf << 4);
      outp[oo] = v[0];
      outp[oo + 4096] = v[1];
      outp[oo + 8192] = v[2];
      outp[oo + 12288] = v[3];
    }
  }
}

// ---------------------------------------------------------------------------
// per-(b,ch) mean / rstd over 4096 pixels (single input)
// ---------------------------------------------------------------------------
__global__ __launch_bounds__(256) void reduce_mv(const float* __restrict__ x,
                                                 float* __restrict__ mr) {
  int bc = blockIdx.x, t = threadIdx.x;
  const float4* xp = (const float4*)(x + ((size_t)bc << 12));
  float s = 0.f, s2 = 0.f;
  for (int i = t; i < 1024; i += 256) {
    float4 v = xp[i];
    s += v.x + v.y + v.z + v.w;
    s2 += v.x * v.x + v.y * v.y + v.z * v.z + v.w * v.w;
  }
#pragma unroll
  for (int off = 32; off; off >>= 1) {
    s += __shfl_down(s, off);
    s2 += __shfl_down(s2, off);
  }
  __shared__ float ls[4], ls2[4];
  int wid = t >> 6, lane = t & 63;
  if (!lane) { ls[wid] = s; ls2[wid] = s2; }
  __syncthreads();
  if (!t) {
    s = ls[0] + ls[1] + ls[2] + ls[3];
    s2 = ls2[0] + ls2[1] + ls2[2] + ls2[3];
    float m = s * (1.f / 4096.f);
    float var = s2 * (1.f / 4096.f) - m * m;
    mr[2 * bc] = m;
    mr[2 * bc + 1] = rsqrtf(fmaxf(var, 0.f) + IN_EPS);
  }
}

// ---------------------------------------------------------------------------
// per-(b,ch) mean / rstd over 4096 pixels of (a + b) (split-K partials)
// ---------------------------------------------------------------------------
__global__ __launch_bounds__(256) void reduce_mv2(const float* __restrict__ xa,
                                                  const float* __restrict__ xb,
                                                  float* __restrict__ mr) {
  int bc = blockIdx.x, t = threadIdx.x;
  const float4* ap = (const float4*)(xa + ((size_t)bc << 12));
  const float4* bp = (const float4*)(xb + ((size_t)bc << 12));
  float s = 0.f, s2 = 0.f;
  for (int i = t; i < 1024; i += 256) {
    float4 va = ap[i], vb = bp[i];
    float x0 = va.x + vb.x, x1 = va.y + vb.y, x2 = va.z + vb.z, x3 = va.w + vb.w;
    s += x0 + x1 + x2 + x3;
    s2 += x0 * x0 + x1 * x1 + x2 * x2 + x3 * x3;
  }
#pragma unroll
  for (int off = 32; off; off >>= 1) {
    s += __shfl_down(s, off);
    s2 += __shfl_down(s2, off);
  }
  __shared__ float ls[4], ls2[4];
  int wid = t >> 6, lane = t & 63;
  if (!lane) { ls[wid] = s; ls2[wid] = s2; }
  __syncthreads();
  if (!t) {
    s = ls[0] + ls[1] + ls[2] + ls[3];
    s2 = ls2[0] + ls2[1] + ls2[2] + ls2[3];
    float m = s * (1.f / 4096.f);
    float var = s2 * (1.f / 4096.f) - m * m;
    mr[2 * bc] = m;
    mr[2 * bc + 1] = rsqrtf(fmaxf(var, 0.f) + IN_EPS);
  }
}

// ---------------------------------------------------------------------------
// out = relu(((a+b) - mean)*rstd); a aliases out (read-before-write per elem)
// ---------------------------------------------------------------------------
__global__ __launch_bounds__(256) void finalize2(const float* __restrict__ ya,
                                                 const float* __restrict__ yb,
                                                 const float* __restrict__ mr,
                                                 float* __restrict__ out) {
  int i = blockIdx.x * 256 + threadIdx.x;
  int bc = i >> 10;
  float m = mr[2 * bc], r = mr[2 * bc + 1];
  float4 va = ((const float4*)ya)[i];
  float4 vb = ((const float4*)yb)[i];
  float4 v;
  v.x = fmaxf((va.x + vb.x - m) * r, 0.f);
  v.y = fmaxf((va.y + vb.y - m) * r, 0.f);
  v.z = fmaxf((va.z + vb.z - m) * r, 0.f);
  v.w = fmaxf((va.w + vb.w - m) * r, 0.f);
  ((float4*)out)[i] = v;
}

extern "C" void kernel_launch(void* const* d_in, const int* in_sizes, int n_in,
                              void* d_out, int out_size, void* d_ws,
                              size_t ws_size, hipStream_t stream) {
  (void)in_sizes; (void)n_in; (void)out_size; (void)ws_size;
  const float* feat  = (const float*)d_in[0];
  const float* guide = (const float*)d_in[1];
  const float* pac_w = (const float*)d_in[2];
  const float* dec_w = (const float*)d_in[3];
  // d_in[4] (dec_b): per-channel constant bias cancels in InstanceNorm mean.
  float* out = (float*)d_out;
  char* ws = (char*)d_ws;

  float* kernbuf = (float*)(ws);                 // 8*9*4096*4   = 0x120000
  short* Ws1     = (short*)(ws + 0x120000);      // 2*36*8192*2  = 0x120000
  short* Ws2     = (short*)(ws + 0x240000);      // 1*36*8192*2  = 0x090000
  float* mr1     = (float*)(ws + 0x2D0000);      // 2048*2*4
  float* mr2     = (float*)(ws + 0x2D4000);      // 1024*2*4
  float* pac     = (float*)(ws + 0x300000);      // 8*256*4096*4 = 0x2000000
  float* ybufB   = (float*)(ws + 0x2300000);     // 8*128*4096*4 = 0x1000000
  // GEMM2 partial ksplit=0 lives in d_out (f32, exact size) -> no extra ws.

  wconv_k<<<(256 * 2304 + 255) / 256, 256, 0, stream>>>(pac_w, Ws1, 256);
  wconv_k<<<(128 * 2304 + 255) / 256, 256, 0, stream>>>(dec_w, Ws2, 128);
  kern_k<<<dim3(64, 8), 256, 0, stream>>>(guide, kernbuf);

  gemm_conv<256, true, false, false><<<dim3(32, 2, 8), 256, 0, stream>>>(
      Ws1, feat, kernbuf, nullptr, pac, nullptr);
  reduce_mv<<<8 * 256, 256, 0, stream>>>(pac, mr1);
  gemm_conv<128, false, true, true><<<dim3(32, 2, 8), 256, 0, stream>>>(
      Ws2, pac, nullptr, mr1, out, ybufB);
  reduce_mv2<<<8 * 128, 256, 0, stream>>>(out, ybufB, mr2);
  finalize2<<<4096, 256, 0, stream>>>(out, ybufB, mr2, out);
}

// Round 11
// 191.893 us; speedup vs baseline: 1.0290x; 1.0290x over previous
//
#include <hip/hip_runtime.h>
#include <hip/hip_bf16.h>
#include <hip/hip_fp16.h>

#define IN_EPS 1e-5f

typedef __attribute__((ext_vector_type(8))) short short8;
typedef __attribute__((ext_vector_type(4))) float f32x4;
typedef _Float16 half8 __attribute__((ext_vector_type(8)));

__device__ __forceinline__ short f2h(float f) {
  __half h = __float2half(f);   // v_cvt_f16_f32 (pairs fuse to cvt_pk)
  return *(short*)&h;
}

// packed multiply: all 8 f16 lanes of v times the f16 broadcast in kbits
__device__ __forceinline__ short8 pkmul(short8 v, unsigned kbits) {
  union { short8 s; unsigned u[4]; } x;
  x.s = v;
  __half2 k = *(__half2*)&kbits;
#pragma unroll
  for (int i = 0; i < 4; ++i) {
    __half2 h = *(__half2*)&x.u[i];
    h = __hmul2(h, k);
    x.u[i] = *(unsigned*)&h;
  }
  return x.s;
}

__device__ __forceinline__ void glds16(const void* g, void* l) {
  typedef const __attribute__((address_space(1))) void gconst_t;
  typedef __attribute__((address_space(3))) void lds_t;
  __builtin_amdgcn_global_load_lds((gconst_t*)g, (lds_t*)l, 16, 0, 0);
}

// ---------------------------------------------------------------------------
// Weight conversion: f32 [O][C][3][3] -> f16 swizzled panel image.
// Panel p = mblk*36 + cb*9 + tap holds [o_local 128][c_local 64], elem at
//   (p<<13) + (ol<<6) + (cl ^ ((ol&7)<<3))
// ---------------------------------------------------------------------------
__global__ void wconv_k(const float* __restrict__ src, short* __restrict__ dst,
                        int O) {
  int idx = blockIdx.x * 256 + threadIdx.x;
  if (idx >= O * 2304) return;
  int o = idx / 2304;
  int r = idx - o * 2304;
  int c = r / 9;
  int k = r - c * 9;
  int mblk = o >> 7, ol = o & 127, cb = c >> 6, cl = c & 63;
  dst[(((size_t)(mblk * 36 + cb * 9 + k)) << 13) + (ol << 6) + (cl ^ ((ol & 7) << 3))]
      = f2h(src[idx]);
}

// ---------------------------------------------------------------------------
// Adaptive Gaussian kernel: kern[b][k][h][w] = exp(-0.5 * sum_c dg^2)
// lane == image col; neighbors via shfl; no barriers in the channel loop.
// ---------------------------------------------------------------------------
__global__ __launch_bounds__(256) void kern_k(const float* __restrict__ g,
                                              float* __restrict__ kern) {
  int h = blockIdx.x, b = blockIdx.y;
  int t = threadIdx.x, w = t & 63, cg = t >> 6;
  float acc[9];
#pragma unroll
  for (int k = 0; k < 9; ++k) acc[k] = 0.f;
  const float* base = g + (((size_t)b * 256 + (cg << 6)) << 12) + (h << 6) + w;
#pragma unroll 4
  for (int cc = 0; cc < 64; ++cc) {
    const float* gp = base + ((size_t)cc << 12);
    float mid = gp[0];
    float top = (h > 0) ? gp[-64] : 0.f;
    float bot = (h < 63) ? gp[64] : 0.f;
    float rows[3] = {top, mid, bot};
#pragma unroll
    for (int i = 0; i < 3; ++i) {
      float v = rows[i];
      float l = __shfl_up(v, 1);
      float r = __shfl_down(v, 1);
      if (w == 0) l = 0.f;
      if (w == 63) r = 0.f;
      float dl = l - mid, dm = v - mid, dr = r - mid;
      acc[i * 3 + 0] += dl * dl;
      acc[i * 3 + 1] += dm * dm;
      acc[i * 3 + 2] += dr * dr;
    }
  }
  __shared__ float red[4][9][64];
#pragma unroll
  for (int k = 0; k < 9; ++k) red[cg][k][w] = acc[k];
  __syncthreads();
  for (int idx = t; idx < 576; idx += 256) {
    int k = idx >> 6, w2 = idx & 63;
    float s = red[0][k][w2] + red[1][k][w2] + red[2][k][w2] + red[3][k][w2];
    kern[(((size_t)b * 9 + k) << 12) + (h << 6) + w2] = expf(-0.5f * s);
  }
}

// ---------------------------------------------------------------------------
// Implicit-GEMM conv, tap-reuse, f16 MFMA. 256 thr / 4 waves (2Mx2N),
// wave tile 64x64. BM=128, BN=128 (2 image rows). K = ncb c-blocks x 9 taps.
// A: double-buffered LDS via global_load_lds (pre-swizzled f16 panels);
//    next panel issued BEFORE compute -> DMA under MFMA; single end-of-step
//    barrier (vmcnt drain) lands it. 1 barrier/interior step.
// B: halo [4 rows][64 cols][64 ch] f16, staged serially at c-block bounds.
// GEMM1 (USE_KERN): kern[tap,px] folded into the B fragment with
//    v_pk_mul_f16 (4 VALU / fragment) -- acc accumulates directly in MFMA.
// GEMM2 (USE_NORM, KSPLIT): norm+relu fused into staging; K split across
//    blockIdx.y; partials to outA / outB.
// ---------------------------------------------------------------------------
template <int MTOT, bool USE_KERN, bool USE_NORM, bool KSPLIT>
__global__ __launch_bounds__(256, 2) void gemm_conv(
    const short* __restrict__ Wimg, const float* __restrict__ X,
    const float* __restrict__ Kf, const float* __restrict__ MRin,
    float* __restrict__ outA, float* __restrict__ outB) {
  __shared__ short ldsA[2][8192];  // [o 128][c 64] swizzled, dbuf, 32KB
  __shared__ short ldsB[16384];    // [r 4][col 64][c 64] swizzled, 32KB
  __shared__ short ldsS[512];      // side halo cols (-1,64): zeros, 1KB
  __shared__ short klds[USE_KERN ? 1152 : 1];  // kern f16 [9][128]

  const int t = threadIdx.x;
  const int nblk = blockIdx.x, b = blockIdx.z;
  const int mblk = KSPLIT ? 0 : blockIdx.y;
  const int cb0 = KSPLIT ? (int)blockIdx.y * 2 : 0;
  const int ncb = KSPLIT ? 2 : 4;
  float* __restrict__ outp = (KSPLIT && blockIdx.y) ? outB : outA;
  const int h0 = nblk * 2;
  const int lane = t & 63, wid = t >> 6;
  const int wr = wid >> 1, wc = wid & 1;
  const int fr = lane & 15, kg = (lane >> 4) << 3;
  const int scol = t & 63, c16 = (t >> 6) << 4;   // B staging: col, 16-ch base

  f32x4 acc[4][4];
#pragma unroll
  for (int i = 0; i < 4; ++i)
#pragma unroll
    for (int j = 0; j < 4; ++j) acc[i][j] = {0.f, 0.f, 0.f, 0.f};

  auto stageA = [&](int pan, int buf) {
    const short* src = Wimg + ((size_t)(mblk * 36 + cb0 * 9 + pan) << 13);
#pragma unroll
    for (int i = 0; i < 4; ++i)
      glds16(src + (((i << 8) + t) << 3),
             &ldsA[buf][((i << 8) + (wid << 6)) << 3]);
  };
  auto stageB = [&](int cbrel) {
    int c0 = ((cb0 + cbrel) << 6) + c16;
    float2 mr[16];
    if (USE_NORM) {
#pragma unroll
      for (int i = 0; i < 16; ++i)
        mr[i] = ((const float2*)MRin)[b * 256 + c0 + i];
    }
#pragma unroll
    for (int r = 0; r < 4; ++r) {
      int hr = h0 - 1 + r;
      bool okr = (unsigned)hr < 64u;
      const float* src = X + (((size_t)b * 256 + c0) << 12) + (hr << 6) + scol;
      short8 pk0, pk1;
#pragma unroll
      for (int i = 0; i < 8; ++i) {
        float x = okr ? src[(size_t)i << 12] : 0.f;
        float y = okr ? src[(size_t)(i + 8) << 12] : 0.f;
        if (USE_NORM) {
          x = fmaxf((x - mr[i].x) * mr[i].y, 0.f);
          y = fmaxf((y - mr[i + 8].x) * mr[i + 8].y, 0.f);
        }
        pk0[i] = f2h(x);
        pk1[i] = f2h(y);
      }
      int base = ((r << 6) + scol) << 6;
      *(short8*)&ldsB[base + (c16 ^ ((scol & 7) << 3))] = pk0;
      *(short8*)&ldsB[base + ((c16 + 8) ^ ((scol & 7) << 3))] = pk1;
    }
  };
  auto computeTap = [&](int tap, int buf) {
    const int di = tap / 3 - 1, dj = tap % 3 - 1;
    const int rw = wc + di + 1;    // halo row for this wave (uniform)
    unsigned kq2[4];
    if (USE_KERN) {
#pragma unroll
      for (int nf = 0; nf < 4; ++nf) {
        short kh = klds[tap * 128 + (wc << 6) + (nf << 4) + fr];
        __half h = *(__half*)&kh;
        __half2 h2 = __half2half2(h);
        kq2[nf] = *(unsigned*)&h2;
      }
    }
    short8 Bf[2][4];
#pragma unroll
    for (int ks = 0; ks < 2; ++ks) {
      int kb = (ks << 5) + kg;
#pragma unroll
      for (int nf = 0; nf < 4; ++nf) {
        int wcol = (nf << 4) + fr + dj;
        int kbs = kb ^ ((wcol & 7) << 3);
        const short* pm = &ldsB[(((rw << 6) + wcol) << 6) + kbs];
        const short* ps = &ldsS[(((rw << 1) + (wcol == 64)) << 6) + kbs];
        short8 bb = *(const short8*)(((unsigned)wcol < 64u) ? pm : ps);
        if (USE_KERN) bb = pkmul(bb, kq2[nf]);
        Bf[ks][nf] = bb;
      }
    }
#pragma unroll
    for (int mf = 0; mf < 4; ++mf) {
      int rr = (wr << 6) + (mf << 4) + fr;
      int xr = (rr & 7) << 3;
      short8 A0 = *(const short8*)&ldsA[buf][(rr << 6) + (kg ^ xr)];
      short8 A1 = *(const short8*)&ldsA[buf][(rr << 6) + ((32 + kg) ^ xr)];
      half8 a0 = *(half8*)&A0, a1 = *(half8*)&A1;
      __builtin_amdgcn_s_setprio(1);
#pragma unroll
      for (int nf = 0; nf < 4; ++nf) {
        acc[mf][nf] = __builtin_amdgcn_mfma_f32_16x16x32_f16(
            a0, *(half8*)&Bf[0][nf], acc[mf][nf], 0, 0, 0);
        acc[mf][nf] = __builtin_amdgcn_mfma_f32_16x16x32_f16(
            a1, *(half8*)&Bf[1][nf], acc[mf][nf], 0, 0, 0);
      }
      __builtin_amdgcn_s_setprio(0);
    }
  };

  // ---- prologue ----
  if (t < 64) {
    short8 z = {0, 0, 0, 0, 0, 0, 0, 0};
    *(short8*)&ldsS[t << 3] = z;
  }
  if (USE_KERN) {
    for (int idx = t; idx < 1152; idx += 256) {
      int tap = idx >> 7, px = idx & 127;
      klds[idx] = f2h(Kf[(((size_t)b * 9 + tap) << 12) +
                         ((h0 + (px >> 6)) << 6) + (px & 63)]);
    }
  }
  stageA(0, 0);
  stageB(0);
  __syncthreads();   // drains glds vmcnt; publishes B / klds / ldsS

  // ---- main loop: ncb c-blocks x 9 taps; 1 barrier per interior step ----
  const int nt = ncb * 9;
  int tap = 0, cbrel = 0;
  for (int pan = 0; pan < nt; ++pan) {
    int buf = pan & 1;
    bool more = (pan + 1) < nt;
    if (more) stageA(pan + 1, buf ^ 1);   // async DMA into idle buffer
    computeTap(tap, buf);
    if (more) {
      __syncthreads();                    // A(pan+1) landed; B readers done
      if (tap == 8) {
        stageB(cbrel + 1);                // serial boundary staging
        __syncthreads();                  // publish new B
      }
    }
    if (++tap == 9) { tap = 0; ++cbrel; }
  }

  // ---- epilogue ----
  const int row4 = (lane >> 4) << 2;
#pragma unroll
  for (int mf = 0; mf < 4; ++mf) {
    int o = (mblk << 7) + (wr << 6) + (mf << 4) + row4;
    size_t ob = (((size_t)b * MTOT + o) << 12) + (nblk << 7) + (wc << 6) + fr;
#pragma unroll
    for (int nf = 0; nf < 4; ++nf) {
      f32x4 v = acc[mf][nf];
      size_t oo = ob + (nf << 4);
      outp[oo] = v[0];
      outp[oo + 4096] = v[1];
      outp[oo + 8192] = v[2];
      outp[oo + 12288] = v[3];
    }
  }
}

// ---------------------------------------------------------------------------
// per-(b,ch) mean / rstd over 4096 pixels (single input)
// ---------------------------------------------------------------------------
__global__ __launch_bounds__(256) void reduce_mv(const float* __restrict__ x,
                                                 float* __restrict__ mr) {
  int bc = blockIdx.x, t = threadIdx.x;
  const float4* xp = (const float4*)(x + ((size_t)bc << 12));
  float s = 0.f, s2 = 0.f;
  for (int i = t; i < 1024; i += 256) {
    float4 v = xp[i];
    s += v.x + v.y + v.z + v.w;
    s2 += v.x * v.x + v.y * v.y + v.z * v.z + v.w * v.w;
  }
#pragma unroll
  for (int off = 32; off; off >>= 1) {
    s += __shfl_down(s, off);
    s2 += __shfl_down(s2, off);
  }
  __shared__ float ls[4], ls2[4];
  int wid = t >> 6, lane = t & 63;
  if (!lane) { ls[wid] = s; ls2[wid] = s2; }
  __syncthreads();
  if (!t) {
    s = ls[0] + ls[1] + ls[2] + ls[3];
    s2 = ls2[0] + ls2[1] + ls2[2] + ls2[3];
    float m = s * (1.f / 4096.f);
    float var = s2 * (1.f / 4096.f) - m * m;
    mr[2 * bc] = m;
    mr[2 * bc + 1] = rsqrtf(fmaxf(var, 0.f) + IN_EPS);
  }
}

// ---------------------------------------------------------------------------
// per-(b,ch) mean / rstd over 4096 pixels of (a + b) (split-K partials)
// ---------------------------------------------------------------------------
__global__ __launch_bounds__(256) void reduce_mv2(const float* __restrict__ xa,
                                                  const float* __restrict__ xb,
                                                  float* __restrict__ mr) {
  int bc = blockIdx.x, t = threadIdx.x;
  const float4* ap = (const float4*)(xa + ((size_t)bc << 12));
  const float4* bp = (const float4*)(xb + ((size_t)bc << 12));
  float s = 0.f, s2 = 0.f;
  for (int i = t; i < 1024; i += 256) {
    float4 va = ap[i], vb = bp[i];
    float x0 = va.x + vb.x, x1 = va.y + vb.y, x2 = va.z + vb.z, x3 = va.w + vb.w;
    s += x0 + x1 + x2 + x3;
    s2 += x0 * x0 + x1 * x1 + x2 * x2 + x3 * x3;
  }
#pragma unroll
  for (int off = 32; off; off >>= 1) {
    s += __shfl_down(s, off);
    s2 += __shfl_down(s2, off);
  }
  __shared__ float ls[4], ls2[4];
  int wid = t >> 6, lane = t & 63;
  if (!lane) { ls[wid] = s; ls2[wid] = s2; }
  __syncthreads();
  if (!t) {
    s = ls[0] + ls[1] + ls[2] + ls[3];
    s2 = ls2[0] + ls2[1] + ls2[2] + ls2[3];
    float m = s * (1.f / 4096.f);
    float var = s2 * (1.f / 4096.f) - m * m;
    mr[2 * bc] = m;
    mr[2 * bc + 1] = rsqrtf(fmaxf(var, 0.f) + IN_EPS);
  }
}

// ---------------------------------------------------------------------------
// out = relu(((a+b) - mean)*rstd); a aliases out (read-before-write per elem)
// ---------------------------------------------------------------------------
__global__ __launch_bounds__(256) void finalize2(const float* __restrict__ ya,
                                                 const float* __restrict__ yb,
                                                 const float* __restrict__ mr,
                                                 float* __restrict__ out) {
  int i = blockIdx.x * 256 + threadIdx.x;
  int bc = i >> 10;
  float m = mr[2 * bc], r = mr[2 * bc + 1];
  float4 va = ((const float4*)ya)[i];
  float4 vb = ((const float4*)yb)[i];
  float4 v;
  v.x = fmaxf((va.x + vb.x - m) * r, 0.f);
  v.y = fmaxf((va.y + vb.y - m) * r, 0.f);
  v.z = fmaxf((va.z + vb.z - m) * r, 0.f);
  v.w = fmaxf((va.w + vb.w - m) * r, 0.f);
  ((float4*)out)[i] = v;
}

extern "C" void kernel_launch(void* const* d_in, const int* in_sizes, int n_in,
                              void* d_out, int out_size, void* d_ws,
                              size_t ws_size, hipStream_t stream) {
  (void)in_sizes; (void)n_in; (void)out_size; (void)ws_size;
  const float* feat  = (const float*)d_in[0];
  const float* guide = (const float*)d_in[1];
  const float* pac_w = (const float*)d_in[2];
  const float* dec_w = (const float*)d_in[3];
  // d_in[4] (dec_b): per-channel constant bias cancels in InstanceNorm mean.
  float* out = (float*)d_out;
  char* ws = (char*)d_ws;

  float* kernbuf = (float*)(ws);                 // 8*9*4096*4   = 0x120000
  short* Ws1     = (short*)(ws + 0x120000);      // 2*36*8192*2  = 0x120000
  short* Ws2     = (short*)(ws + 0x240000);      // 1*36*8192*2  = 0x090000
  float* mr1     = (float*)(ws + 0x2D0000);      // 2048*2*4
  float* mr2     = (float*)(ws + 0x2D4000);      // 1024*2*4
  float* pac     = (float*)(ws + 0x300000);      // 8*256*4096*4 = 0x2000000
  float* ybufB   = (float*)(ws + 0x2300000);     // 8*128*4096*4 = 0x1000000
  // GEMM2 partial ksplit=0 lives in d_out (f32, exact size) -> no extra ws.

  wconv_k<<<(256 * 2304 + 255) / 256, 256, 0, stream>>>(pac_w, Ws1, 256);
  wconv_k<<<(128 * 2304 + 255) / 256, 256, 0, stream>>>(dec_w, Ws2, 128);
  kern_k<<<dim3(64, 8), 256, 0, stream>>>(guide, kernbuf);

  gemm_conv<256, true, false, false><<<dim3(32, 2, 8), 256, 0, stream>>>(
      Ws1, feat, kernbuf, nullptr, pac, nullptr);
  reduce_mv<<<8 * 256, 256, 0, stream>>>(pac, mr1);
  gemm_conv<128, false, true, true><<<dim3(32, 2, 8), 256, 0, stream>>>(
      Ws2, pac, nullptr, mr1, out, ybufB);
  reduce_mv2<<<8 * 128, 256, 0, stream>>>(out, ybufB, mr2);
  finalize2<<<4096, 256, 0, stream>>>(out, ybufB, mr2, out);
}

// Round 12
// 137.969 us; speedup vs baseline: 1.4311x; 1.3908x over previous
//
#include <hip/hip_runtime.h>
#include <hip/hip_bf16.h>
#include <hip/hip_fp16.h>

#define IN_EPS 1e-5f

typedef __attribute__((ext_vector_type(8))) short short8;
typedef __attribute__((ext_vector_type(4))) float f32x4;
typedef _Float16 half8 __attribute__((ext_vector_type(8)));

__device__ __forceinline__ short f2h(float f) {
  __half h = __float2half(f);
  return *(short*)&h;
}

// packed multiply: all 8 f16 lanes of v times the f16 broadcast pair in kbits
__device__ __forceinline__ short8 pkmul(short8 v, unsigned kbits) {
  union { short8 s; unsigned u[4]; } x;
  x.s = v;
  __half2 k = *(__half2*)&kbits;
#pragma unroll
  for (int i = 0; i < 4; ++i) {
    __half2 h = *(__half2*)&x.u[i];
    h = __hmul2(h, k);
    x.u[i] = *(unsigned*)&h;
  }
  return x.s;
}

// ---------------------------------------------------------------------------
// Weight conversion: f32 [O][C][3][3] -> f16 swizzled panel image.
// Panel p = mblk*36 + cb*9 + tap holds [o_local 128][c_local 64], elem at
//   (p<<13) + (ol<<6) + (cl ^ ((ol&7)<<3))
// ---------------------------------------------------------------------------
__global__ void wconv_k(const float* __restrict__ src, short* __restrict__ dst,
                        int O) {
  int idx = blockIdx.x * 256 + threadIdx.x;
  if (idx >= O * 2304) return;
  int o = idx / 2304;
  int r = idx - o * 2304;
  int c = r / 9;
  int k = r - c * 9;
  int mblk = o >> 7, ol = o & 127, cb = c >> 6, cl = c & 63;
  dst[(((size_t)(mblk * 36 + cb * 9 + k)) << 13) + (ol << 6) + (cl ^ ((ol & 7) << 3))]
      = f2h(src[idx]);
}

// ---------------------------------------------------------------------------
// Adaptive Gaussian kernel: kern[b][k][h][w] = exp(-0.5 * sum_c dg^2)
// lane == image col; neighbors via shfl; no barriers in the channel loop.
// ---------------------------------------------------------------------------
__global__ __launch_bounds__(256) void kern_k(const float* __restrict__ g,
                                              float* __restrict__ kern) {
  int h = blockIdx.x, b = blockIdx.y;
  int t = threadIdx.x, w = t & 63, cg = t >> 6;
  float acc[9];
#pragma unroll
  for (int k = 0; k < 9; ++k) acc[k] = 0.f;
  const float* base = g + (((size_t)b * 256 + (cg << 6)) << 12) + (h << 6) + w;
#pragma unroll 4
  for (int cc = 0; cc < 64; ++cc) {
    const float* gp = base + ((size_t)cc << 12);
    float mid = gp[0];
    float top = (h > 0) ? gp[-64] : 0.f;
    float bot = (h < 63) ? gp[64] : 0.f;
    float rows[3] = {top, mid, bot};
#pragma unroll
    for (int i = 0; i < 3; ++i) {
      float v = rows[i];
      float l = __shfl_up(v, 1);
      float r = __shfl_down(v, 1);
      if (w == 0) l = 0.f;
      if (w == 63) r = 0.f;
      float dl = l - mid, dm = v - mid, dr = r - mid;
      acc[i * 3 + 0] += dl * dl;
      acc[i * 3 + 1] += dm * dm;
      acc[i * 3 + 2] += dr * dr;
    }
  }
  __shared__ float red[4][9][64];
#pragma unroll
  for (int k = 0; k < 9; ++k) red[cg][k][w] = acc[k];
  __syncthreads();
  for (int idx = t; idx < 576; idx += 256) {
    int k = idx >> 6, w2 = idx & 63;
    float s = red[0][k][w2] + red[1][k][w2] + red[2][k][w2] + red[3][k][w2];
    kern[(((size_t)b * 9 + k) << 12) + (h << 6) + w2] = expf(-0.5f * s);
  }
}

// ---------------------------------------------------------------------------
// Implicit-GEMM conv with tap-reuse (R9 structure, f16). BM=128, BN=128,
// 512 thr / 8 waves (2M x 4N, wave tile 64x32). K = ncb c-blocks x 9 taps.
// A: LDS dbuf, reg-staged; write into the idle buffer pre-barrier ->
//    ONE barrier per non-boundary step.
// B: halo [4 rows][64 cols][64 ch] f16, staged once per c-block
//    (GEMM1: T14 issue-early; GEMM2: serial at boundary).
// GEMM1 (USE_KERN): kern[tap,px] folded into B fragment via v_pk_mul_f16
//    (4 VALU per fragment) -- acc accumulates directly in the MFMA pipe.
// GEMM2 (USE_NORM, KSPLIT): norm+relu fused into staging; K split across
//    blockIdx.y; partials written to outA / outB.
// ---------------------------------------------------------------------------
template <int MTOT, bool USE_KERN, bool USE_NORM, bool KSPLIT>
__global__ __launch_bounds__(512, 4) void gemm_conv(
    const short* __restrict__ Wimg, const float* __restrict__ X,
    const float* __restrict__ Kf, const float* __restrict__ MRin,
    float* __restrict__ outA, float* __restrict__ outB) {
  __shared__ short ldsA[2][8192];  // [o 128][c 64] swizzled, dbuf, 32KB
  __shared__ short ldsB[16384];    // [r 4][col 64][c 64] swizzled, 32KB
  __shared__ short ldsS[512];      // side halo cols (-1,64): zeros, 1KB
  __shared__ short klds[USE_KERN ? 1152 : 1];  // kern f16 [9][128]

  const int t = threadIdx.x;
  const int nblk = blockIdx.x, b = blockIdx.z;
  const int mblk = KSPLIT ? 0 : blockIdx.y;
  const int cb0 = KSPLIT ? (int)blockIdx.y * 2 : 0;
  const int ncb = KSPLIT ? 2 : 4;
  float* __restrict__ outp = (KSPLIT && blockIdx.y) ? outB : outA;
  const int h0 = nblk * 2;
  const int lane = t & 63, wid = t >> 6;
  const int wr = wid >> 2, wc = wid & 3;
  const int fr = lane & 15, kg = (lane >> 4) << 3;
  const int scol = t & 63, c8 = (t >> 6) << 3;   // B staging: col, 8-ch base

  f32x4 acc[4][2];
#pragma unroll
  for (int i = 0; i < 4; ++i)
#pragma unroll
    for (int j = 0; j < 2; ++j) acc[i][j] = {0.f, 0.f, 0.f, 0.f};

  float breg[4][8];
  float2 mreg[8];

  auto loadA = [&](int pan, short8* ar) {
    const short* src =
        Wimg + (((size_t)(mblk * 36 + cb0 * 9 + pan)) << 13) + (t << 3);
    ar[0] = *(const short8*)(src);
    ar[1] = *(const short8*)(src + 4096);
  };
  auto writeA = [&](const short8* ar, int buf) {
    *(short8*)&ldsA[buf][t << 3] = ar[0];
    *(short8*)&ldsA[buf][4096 + (t << 3)] = ar[1];
  };
  auto loadBregs = [&](int cbrel) {
    int c0 = ((cb0 + cbrel) << 6) + c8;
    const float* base = X + (((size_t)b * 256 + c0) << 12) + scol;
    if (USE_NORM) {
#pragma unroll
      for (int i = 0; i < 8; ++i)
        mreg[i] = ((const float2*)MRin)[b * 256 + c0 + i];
    }
#pragma unroll
    for (int r = 0; r < 4; ++r) {
      int hr = h0 - 1 + r;
      bool okr = (unsigned)hr < 64u;
      const float* src = base + (hr << 6);
#pragma unroll
      for (int i = 0; i < 8; ++i)
        breg[r][i] = okr ? src[(size_t)i << 12] : 0.f;
    }
  };
  auto writeB = [&]() {
#pragma unroll
    for (int r = 0; r < 4; ++r) {
      short8 pk;
#pragma unroll
      for (int i = 0; i < 8; ++i) {
        float x = breg[r][i];
        if (USE_NORM) x = fmaxf((x - mreg[i].x) * mreg[i].y, 0.f);
        pk[i] = f2h(x);
      }
      *(short8*)&ldsB[(((r << 6) + scol) << 6) + (c8 ^ ((scol & 7) << 3))] = pk;
    }
  };
  auto computeTap = [&](int tap, int buf) {
    const int di = tap / 3 - 1, dj = tap % 3 - 1;
    unsigned kq2[2];
    if (USE_KERN) {
#pragma unroll
      for (int nf = 0; nf < 2; ++nf) {
        short kh = klds[tap * 128 + (wc << 5) + (nf << 4) + fr];
        __half h = *(__half*)&kh;
        __half2 h2 = __half2half2(h);
        kq2[nf] = *(unsigned*)&h2;
      }
    }
#pragma unroll
    for (int ks = 0; ks < 2; ++ks) {
      int kb = (ks << 5) + kg;
      short8 a4[4], b2[2];
#pragma unroll
      for (int mf = 0; mf < 4; ++mf) {
        int rr = (wr << 6) + (mf << 4) + fr;
        a4[mf] = *(const short8*)&ldsA[buf][(rr << 6) + (kb ^ ((rr & 7) << 3))];
      }
#pragma unroll
      for (int nf = 0; nf < 2; ++nf) {
        int px = (wc << 5) + (nf << 4) + fr;
        int rr2 = (px >> 6) + di + 1;
        int wcol = (px & 63) + dj;
        int kbs = kb ^ ((wcol & 7) << 3);
        const short* pm = &ldsB[(((rr2 << 6) + wcol) << 6) + kbs];
        const short* ps = &ldsS[(((rr2 << 1) + (wcol == 64)) << 6) + kbs];
        short8 bb = *(const short8*)(((unsigned)wcol < 64u) ? pm : ps);
        if (USE_KERN) bb = pkmul(bb, kq2[nf]);
        b2[nf] = bb;
      }
      __builtin_amdgcn_s_setprio(1);
#pragma unroll
      for (int mf = 0; mf < 4; ++mf)
#pragma unroll
        for (int nf = 0; nf < 2; ++nf)
          acc[mf][nf] = __builtin_amdgcn_mfma_f32_16x16x32_f16(
              *(half8*)&a4[mf], *(half8*)&b2[nf], acc[mf][nf], 0, 0, 0);
      __builtin_amdgcn_s_setprio(0);
    }
  };

  // ---- prologue ----
  if (t < 64) {
    short8 z = {0, 0, 0, 0, 0, 0, 0, 0};
    *(short8*)&ldsS[t << 3] = z;
  }
  if (USE_KERN) {
    for (int idx = t; idx < 1152; idx += 512) {
      int tap = idx >> 7, px = idx & 127;
      klds[idx] = f2h(Kf[(((size_t)b * 9 + tap) << 12) +
                         ((h0 + (px >> 6)) << 6) + (px & 63)]);
    }
  }
  {
    short8 ar[2];
    loadA(0, ar);
    loadBregs(0);
    writeA(ar, 0);
    writeB();
  }
  __syncthreads();

  // ---- main loop: ncb c-blocks x 9 taps; 1 barrier per interior step ----
  const int nt = ncb * 9;
  int tap = 0, cbrel = 0;
  for (int pan = 0; pan < nt; ++pan) {
    int buf = pan & 1;
    bool more = (pan + 1) < nt;
    bool lastTap = (tap == 8);
    short8 ar[2];
    if (more) loadA(pan + 1, ar);                       // overlaps compute
    if (USE_KERN && more && lastTap) loadBregs(cbrel + 1);  // T14 issue-early
    computeTap(tap, buf);
    if (more && lastTap) {
      __syncthreads();                 // B readers done
      if (!USE_NORM) {
        writeB();
      } else {
        loadBregs(cbrel + 1);          // serial staging (register safety)
        writeB();
      }
      writeA(ar, buf ^ 1);
      __syncthreads();                 // publish A+B
    } else if (more) {
      writeA(ar, buf ^ 1);             // idle buffer: no pre-write barrier
      __syncthreads();                 // publish A
    }
    if (++tap == 9) { tap = 0; ++cbrel; }
  }

  // ---- epilogue ----
  const int row4 = (lane >> 4) << 2;
#pragma unroll
  for (int mf = 0; mf < 4; ++mf) {
    int o = (mblk << 7) + (wr << 6) + (mf << 4) + row4;
    size_t ob = (((size_t)b * MTOT + o) << 12) + (nblk << 7) + (wc << 5) + fr;
#pragma unroll
    for (int nf = 0; nf < 2; ++nf) {
      f32x4 v = acc[mf][nf];
      size_t oo = ob + (nf << 4);
      outp[oo] = v[0];
      outp[oo + 4096] = v[1];
      outp[oo + 8192] = v[2];
      outp[oo + 12288] = v[3];
    }
  }
}

// ---------------------------------------------------------------------------
// per-(b,ch) mean / rstd over 4096 pixels (single input)
// ---------------------------------------------------------------------------
__global__ __launch_bounds__(256) void reduce_mv(const float* __restrict__ x,
                                                 float* __restrict__ mr) {
  int bc = blockIdx.x, t = threadIdx.x;
  const float4* xp = (const float4*)(x + ((size_t)bc << 12));
  float s = 0.f, s2 = 0.f;
  for (int i = t; i < 1024; i += 256) {
    float4 v = xp[i];
    s += v.x + v.y + v.z + v.w;
    s2 += v.x * v.x + v.y * v.y + v.z * v.z + v.w * v.w;
  }
#pragma unroll
  for (int off = 32; off; off >>= 1) {
    s += __shfl_down(s, off);
    s2 += __shfl_down(s2, off);
  }
  __shared__ float ls[4], ls2[4];
  int wid = t >> 6, lane = t & 63;
  if (!lane) { ls[wid] = s; ls2[wid] = s2; }
  __syncthreads();
  if (!t) {
    s = ls[0] + ls[1] + ls[2] + ls[3];
    s2 = ls2[0] + ls2[1] + ls2[2] + ls2[3];
    float m = s * (1.f / 4096.f);
    float var = s2 * (1.f / 4096.f) - m * m;
    mr[2 * bc] = m;
    mr[2 * bc + 1] = rsqrtf(fmaxf(var, 0.f) + IN_EPS);
  }
}

// ---------------------------------------------------------------------------
// per-(b,ch) mean / rstd over 4096 pixels of (a + b) (split-K partials)
// ---------------------------------------------------------------------------
__global__ __launch_bounds__(256) void reduce_mv2(const float* __restrict__ xa,
                                                  const float* __restrict__ xb,
                                                  float* __restrict__ mr) {
  int bc = blockIdx.x, t = threadIdx.x;
  const float4* ap = (const float4*)(xa + ((size_t)bc << 12));
  const float4* bp = (const float4*)(xb + ((size_t)bc << 12));
  float s = 0.f, s2 = 0.f;
  for (int i = t; i < 1024; i += 256) {
    float4 va = ap[i], vb = bp[i];
    float x0 = va.x + vb.x, x1 = va.y + vb.y, x2 = va.z + vb.z, x3 = va.w + vb.w;
    s += x0 + x1 + x2 + x3;
    s2 += x0 * x0 + x1 * x1 + x2 * x2 + x3 * x3;
  }
#pragma unroll
  for (int off = 32; off; off >>= 1) {
    s += __shfl_down(s, off);
    s2 += __shfl_down(s2, off);
  }
  __shared__ float ls[4], ls2[4];
  int wid = t >> 6, lane = t & 63;
  if (!lane) { ls[wid] = s; ls2[wid] = s2; }
  __syncthreads();
  if (!t) {
    s = ls[0] + ls[1] + ls[2] + ls[3];
    s2 = ls2[0] + ls2[1] + ls2[2] + ls2[3];
    float m = s * (1.f / 4096.f);
    float var = s2 * (1.f / 4096.f) - m * m;
    mr[2 * bc] = m;
    mr[2 * bc + 1] = rsqrtf(fmaxf(var, 0.f) + IN_EPS);
  }
}

// ---------------------------------------------------------------------------
// out = relu(((a+b) - mean)*rstd); a aliases out (read-before-write per elem)
// ---------------------------------------------------------------------------
__global__ __launch_bounds__(256) void finalize2(const float* __restrict__ ya,
                                                 const float* __restrict__ yb,
                                                 const float* __restrict__ mr,
                                                 float* __restrict__ out) {
  int i = blockIdx.x * 256 + threadIdx.x;
  int bc = i >> 10;
  float m = mr[2 * bc], r = mr[2 * bc + 1];
  float4 va = ((const float4*)ya)[i];
  float4 vb = ((const float4*)yb)[i];
  float4 v;
  v.x = fmaxf((va.x + vb.x - m) * r, 0.f);
  v.y = fmaxf((va.y + vb.y - m) * r, 0.f);
  v.z = fmaxf((va.z + vb.z - m) * r, 0.f);
  v.w = fmaxf((va.w + vb.w - m) * r, 0.f);
  ((float4*)out)[i] = v;
}

extern "C" void kernel_launch(void* const* d_in, const int* in_sizes, int n_in,
                              void* d_out, int out_size, void* d_ws,
                              size_t ws_size, hipStream_t stream) {
  (void)in_sizes; (void)n_in; (void)out_size; (void)ws_size;
  const float* feat  = (const float*)d_in[0];
  const float* guide = (const float*)d_in[1];
  const float* pac_w = (const float*)d_in[2];
  const float* dec_w = (const float*)d_in[3];
  // d_in[4] (dec_b): per-channel constant bias cancels in InstanceNorm mean.
  float* out = (float*)d_out;
  char* ws = (char*)d_ws;

  float* kernbuf = (float*)(ws);                 // 8*9*4096*4   = 0x120000
  short* Ws1     = (short*)(ws + 0x120000);      // 2*36*8192*2  = 0x120000
  short* Ws2     = (short*)(ws + 0x240000);      // 1*36*8192*2  = 0x090000
  float* mr1     = (float*)(ws + 0x2D0000);      // 2048*2*4
  float* mr2     = (float*)(ws + 0x2D4000);      // 1024*2*4
  float* pac     = (float*)(ws + 0x300000);      // 8*256*4096*4 = 0x2000000
  float* ybufB   = (float*)(ws + 0x2300000);     // 8*128*4096*4 = 0x1000000
  // GEMM2 partial ksplit=0 lives in d_out (f32, exact size) -> no extra ws.

  wconv_k<<<(256 * 2304 + 255) / 256, 256, 0, stream>>>(pac_w, Ws1, 256);
  wconv_k<<<(128 * 2304 + 255) / 256, 256, 0, stream>>>(dec_w, Ws2, 128);
  kern_k<<<dim3(64, 8), 256, 0, stream>>>(guide, kernbuf);

  gemm_conv<256, true, false, false><<<dim3(32, 2, 8), 512, 0, stream>>>(
      Ws1, feat, kernbuf, nullptr, pac, nullptr);
  reduce_mv<<<8 * 256, 256, 0, stream>>>(pac, mr1);
  gemm_conv<128, false, true, true><<<dim3(32, 2, 8), 512, 0, stream>>>(
      Ws2, pac, nullptr, mr1, out, ybufB);
  reduce_mv2<<<8 * 128, 256, 0, stream>>>(out, ybufB, mr2);
  finalize2<<<4096, 256, 0, stream>>>(out, ybufB, mr2, out);
}

// Round 14
// 136.250 us; speedup vs baseline: 1.4492x; 1.0126x over previous
//
#include <hip/hip_runtime.h>
#include <hip/hip_bf16.h>
#include <hip/hip_fp16.h>

#define IN_EPS 1e-5f

typedef __attribute__((ext_vector_type(8))) short short8;
typedef __attribute__((ext_vector_type(4))) float f32x4;
typedef _Float16 half8 __attribute__((ext_vector_type(8)));

__device__ __forceinline__ short f2h(float f) {
  __half h = __float2half(f);
  return *(short*)&h;
}
__device__ __forceinline__ float h2f(short s) {
  __half h = *(__half*)&s;
  return __half2float(h);
}

// packed multiply: all 8 f16 lanes of v times the f16 broadcast pair in kbits
__device__ __forceinline__ short8 pkmul(short8 v, unsigned kbits) {
  union { short8 s; unsigned u[4]; } x;
  x.s = v;
  __half2 k = *(__half2*)&kbits;
#pragma unroll
  for (int i = 0; i < 4; ++i) {
    __half2 h = *(__half2*)&x.u[i];
    h = __hmul2(h, k);
    x.u[i] = *(unsigned*)&h;
  }
  return x.s;
}

// ---------------------------------------------------------------------------
// Weight conversion: f32 [O][C][3][3] -> f16 swizzled panel image.
// Panel p = mblk*36 + cb*9 + tap holds [o_local 128][c_local 64], elem at
//   (p<<13) + (ol<<6) + (cl ^ ((ol&7)<<3))
// ---------------------------------------------------------------------------
__global__ void wconv_k(const float* __restrict__ src, short* __restrict__ dst,
                        int O) {
  int idx = blockIdx.x * 256 + threadIdx.x;
  if (idx >= O * 2304) return;
  int o = idx / 2304;
  int r = idx - o * 2304;
  int c = r / 9;
  int k = r - c * 9;
  int mblk = o >> 7, ol = o & 127, cb = c >> 6, cl = c & 63;
  dst[(((size_t)(mblk * 36 + cb * 9 + k)) << 13) + (ol << 6) + (cl ^ ((ol & 7) << 3))]
      = f2h(src[idx]);
}

// ---------------------------------------------------------------------------
// Adaptive Gaussian kernel: kern[b][k][h][w] = exp(-0.5 * sum_c dg^2)
// lane == image col; neighbors via shfl; no barriers in the channel loop.
// ---------------------------------------------------------------------------
__global__ __launch_bounds__(256) void kern_k(const float* __restrict__ g,
                                              float* __restrict__ kern) {
  int h = blockIdx.x, b = blockIdx.y;
  int t = threadIdx.x, w = t & 63, cg = t >> 6;
  float acc[9];
#pragma unroll
  for (int k = 0; k < 9; ++k) acc[k] = 0.f;
  const float* base = g + (((size_t)b * 256 + (cg << 6)) << 12) + (h << 6) + w;
#pragma unroll 4
  for (int cc = 0; cc < 64; ++cc) {
    const float* gp = base + ((size_t)cc << 12);
    float mid = gp[0];
    float top = (h > 0) ? gp[-64] : 0.f;
    float bot = (h < 63) ? gp[64] : 0.f;
    float rows[3] = {top, mid, bot};
#pragma unroll
    for (int i = 0; i < 3; ++i) {
      float v = rows[i];
      float l = __shfl_up(v, 1);
      float r = __shfl_down(v, 1);
      if (w == 0) l = 0.f;
      if (w == 63) r = 0.f;
      float dl = l - mid, dm = v - mid, dr = r - mid;
      acc[i * 3 + 0] += dl * dl;
      acc[i * 3 + 1] += dm * dm;
      acc[i * 3 + 2] += dr * dr;
    }
  }
  __shared__ float red[4][9][64];
#pragma unroll
  for (int k = 0; k < 9; ++k) red[cg][k][w] = acc[k];
  __syncthreads();
  for (int idx = t; idx < 576; idx += 256) {
    int k = idx >> 6, w2 = idx & 63;
    float s = red[0][k][w2] + red[1][k][w2] + red[2][k][w2] + red[3][k][w2];
    kern[(((size_t)b * 9 + k) << 12) + (h << 6) + w2] = expf(-0.5f * s);
  }
}

// ---------------------------------------------------------------------------
// Implicit-GEMM conv with tap-reuse (R12 structure, f16 in/out). BM=128,
// BN=128, 512 thr / 8 waves (2M x 4N, wave tile 64x32). K = ncb cblk x 9 taps.
// A: LDS dbuf, reg-staged; ONE barrier per non-boundary step.
// B: halo [4 rows][64 cols][64 ch] f16, staged once per c-block.
// X input: f32 (GEMM1/feat) or f16 (GEMM2/pac) via XF16.
// Output: f16 (pac or split-K partials).
// GEMM1 (USE_KERN): kern folded into B fragment via v_pk_mul_f16.
// GEMM2 (USE_NORM, KSPLIT): norm+relu fused into staging; K split across
//    blockIdx.y; f16 partials to outA / outB.
// ---------------------------------------------------------------------------
template <int MTOT, bool USE_KERN, bool USE_NORM, bool KSPLIT, bool XF16>
__global__ __launch_bounds__(512, 4) void gemm_conv(
    const short* __restrict__ Wimg, const void* __restrict__ Xv,
    const float* __restrict__ Kf, const float* __restrict__ MRin,
    short* __restrict__ outA, short* __restrict__ outB) {
  __shared__ short ldsA[2][8192];  // [o 128][c 64] swizzled, dbuf, 32KB
  __shared__ short ldsB[16384];    // [r 4][col 64][c 64] swizzled, 32KB
  __shared__ short ldsS[512];      // side halo cols (-1,64): zeros, 1KB
  __shared__ short klds[USE_KERN ? 1152 : 1];  // kern f16 [9][128]

  const int t = threadIdx.x;
  const int nblk = blockIdx.x, b = blockIdx.z;
  const int mblk = KSPLIT ? 0 : blockIdx.y;
  const int cb0 = KSPLIT ? (int)blockIdx.y * 2 : 0;
  const int ncb = KSPLIT ? 2 : 4;
  short* __restrict__ outp = (KSPLIT && blockIdx.y) ? outB : outA;
  const int h0 = nblk * 2;
  const int lane = t & 63, wid = t >> 6;
  const int wr = wid >> 2, wc = wid & 3;
  const int fr = lane & 15, kg = (lane >> 4) << 3;
  const int scol = t & 63, c8 = (t >> 6) << 3;   // B staging: col, 8-ch base

  f32x4 acc[4][2];
#pragma unroll
  for (int i = 0; i < 4; ++i)
#pragma unroll
    for (int j = 0; j < 2; ++j) acc[i][j] = {0.f, 0.f, 0.f, 0.f};

  float breg[4][8];
  float2 mreg[8];

  auto loadA = [&](int pan, short8* ar) {
    const short* src =
        Wimg + (((size_t)(mblk * 36 + cb0 * 9 + pan)) << 13) + (t << 3);
    ar[0] = *(const short8*)(src);
    ar[1] = *(const short8*)(src + 4096);
  };
  auto writeA = [&](const short8* ar, int buf) {
    *(short8*)&ldsA[buf][t << 3] = ar[0];
    *(short8*)&ldsA[buf][4096 + (t << 3)] = ar[1];
  };
  auto loadBregs = [&](int cbrel) {
    int c0 = ((cb0 + cbrel) << 6) + c8;
    size_t off = (((size_t)b * 256 + c0) << 12) + scol;
    if (USE_NORM) {
#pragma unroll
      for (int i = 0; i < 8; ++i)
        mreg[i] = ((const float2*)MRin)[b * 256 + c0 + i];
    }
#pragma unroll
    for (int r = 0; r < 4; ++r) {
      int hr = h0 - 1 + r;
      bool okr = (unsigned)hr < 64u;
#pragma unroll
      for (int i = 0; i < 8; ++i) {
        if (XF16) {
          const short* src = (const short*)Xv + off + (hr << 6);
          breg[r][i] = okr ? h2f(src[(size_t)i << 12]) : 0.f;
        } else {
          const float* src = (const float*)Xv + off + (hr << 6);
          breg[r][i] = okr ? src[(size_t)i << 12] : 0.f;
        }
      }
    }
  };
  auto writeB = [&]() {
#pragma unroll
    for (int r = 0; r < 4; ++r) {
      short8 pk;
#pragma unroll
      for (int i = 0; i < 8; ++i) {
        float x = breg[r][i];
        if (USE_NORM) x = fmaxf((x - mreg[i].x) * mreg[i].y, 0.f);
        pk[i] = f2h(x);
      }
      *(short8*)&ldsB[(((r << 6) + scol) << 6) + (c8 ^ ((scol & 7) << 3))] = pk;
    }
  };
  auto computeTap = [&](int tap, int buf) {
    const int di = tap / 3 - 1, dj = tap % 3 - 1;
    unsigned kq2[2];
    if (USE_KERN) {
#pragma unroll
      for (int nf = 0; nf < 2; ++nf) {
        short kh = klds[tap * 128 + (wc << 5) + (nf << 4) + fr];
        __half h = *(__half*)&kh;
        __half2 h2 = __half2half2(h);
        kq2[nf] = *(unsigned*)&h2;
      }
    }
#pragma unroll
    for (int ks = 0; ks < 2; ++ks) {
      int kb = (ks << 5) + kg;
      short8 a4[4], b2[2];
#pragma unroll
      for (int mf = 0; mf < 4; ++mf) {
        int rr = (wr << 6) + (mf << 4) + fr;
        a4[mf] = *(const short8*)&ldsA[buf][(rr << 6) + (kb ^ ((rr & 7) << 3))];
      }
#pragma unroll
      for (int nf = 0; nf < 2; ++nf) {
        int px = (wc << 5) + (nf << 4) + fr;
        int rr2 = (px >> 6) + di + 1;
        int wcol = (px & 63) + dj;
        int kbs = kb ^ ((wcol & 7) << 3);
        const short* pm = &ldsB[(((rr2 << 6) + wcol) << 6) + kbs];
        const short* ps = &ldsS[(((rr2 << 1) + (wcol == 64)) << 6) + kbs];
        short8 bb = *(const short8*)(((unsigned)wcol < 64u) ? pm : ps);
        if (USE_KERN) bb = pkmul(bb, kq2[nf]);
        b2[nf] = bb;
      }
      __builtin_amdgcn_s_setprio(1);
#pragma unroll
      for (int mf = 0; mf < 4; ++mf)
#pragma unroll
        for (int nf = 0; nf < 2; ++nf)
          acc[mf][nf] = __builtin_amdgcn_mfma_f32_16x16x32_f16(
              *(half8*)&a4[mf], *(half8*)&b2[nf], acc[mf][nf], 0, 0, 0);
      __builtin_amdgcn_s_setprio(0);
    }
  };

  // ---- prologue ----
  if (t < 64) {
    short8 z = {0, 0, 0, 0, 0, 0, 0, 0};
    *(short8*)&ldsS[t << 3] = z;
  }
  if (USE_KERN) {
    for (int idx = t; idx < 1152; idx += 512) {
      int tap = idx >> 7, px = idx & 127;
      klds[idx] = f2h(Kf[(((size_t)b * 9 + tap) << 12) +
                         ((h0 + (px >> 6)) << 6) + (px & 63)]);
    }
  }
  {
    short8 ar[2];
    loadA(0, ar);
    loadBregs(0);
    writeA(ar, 0);
    writeB();
  }
  __syncthreads();

  // ---- main loop: ncb c-blocks x 9 taps; 1 barrier per interior step ----
  const int nt = ncb * 9;
  int tap = 0, cbrel = 0;
  for (int pan = 0; pan < nt; ++pan) {
    int buf = pan & 1;
    bool more = (pan + 1) < nt;
    bool lastTap = (tap == 8);
    short8 ar[2];
    if (more) loadA(pan + 1, ar);                       // overlaps compute
    if (USE_KERN && more && lastTap) loadBregs(cbrel + 1);  // T14 issue-early
    computeTap(tap, buf);
    if (more && lastTap) {
      __syncthreads();                 // B readers done
      if (!USE_NORM) {
        writeB();
      } else {
        loadBregs(cbrel + 1);          // serial staging (register safety)
        writeB();
      }
      writeA(ar, buf ^ 1);
      __syncthreads();                 // publish A+B
    } else if (more) {
      writeA(ar, buf ^ 1);             // idle buffer: no pre-write barrier
      __syncthreads();                 // publish A
    }
    if (++tap == 9) { tap = 0; ++cbrel; }
  }

  // ---- epilogue: f16 out ----
  const int row4 = (lane >> 4) << 2;
#pragma unroll
  for (int mf = 0; mf < 4; ++mf) {
    int o = (mblk << 7) + (wr << 6) + (mf << 4) + row4;
    size_t ob = (((size_t)b * MTOT + o) << 12) + (nblk << 7) + (wc << 5) + fr;
#pragma unroll
    for (int nf = 0; nf < 2; ++nf) {
      f32x4 v = acc[mf][nf];
      size_t oo = ob + (nf << 4);
      outp[oo] = f2h(v[0]);
      outp[oo + 4096] = f2h(v[1]);
      outp[oo + 8192] = f2h(v[2]);
      outp[oo + 12288] = f2h(v[3]);
    }
  }
}

// ---------------------------------------------------------------------------
// per-(b,ch) mean / rstd over 4096 pixels of f16 input
// ---------------------------------------------------------------------------
__global__ __launch_bounds__(256) void reduce_mv(const short* __restrict__ x,
                                                 float* __restrict__ mr) {
  int bc = blockIdx.x, t = threadIdx.x;
  const short8* xp = (const short8*)(x + ((size_t)bc << 12));
  float s = 0.f, s2 = 0.f;
  for (int i = t; i < 512; i += 256) {
    short8 v = xp[i];
#pragma unroll
    for (int j = 0; j < 8; ++j) {
      float f = h2f(v[j]);
      s += f;
      s2 += f * f;
    }
  }
#pragma unroll
  for (int off = 32; off; off >>= 1) {
    s += __shfl_down(s, off);
    s2 += __shfl_down(s2, off);
  }
  __shared__ float ls[4], ls2[4];
  int wid = t >> 6, lane = t & 63;
  if (!lane) { ls[wid] = s; ls2[wid] = s2; }
  __syncthreads();
  if (!t) {
    s = ls[0] + ls[1] + ls[2] + ls[3];
    s2 = ls2[0] + ls2[1] + ls2[2] + ls2[3];
    float m = s * (1.f / 4096.f);
    float var = s2 * (1.f / 4096.f) - m * m;
    mr[2 * bc] = m;
    mr[2 * bc + 1] = rsqrtf(fmaxf(var, 0.f) + IN_EPS);
  }
}

// ---------------------------------------------------------------------------
// per-(b,ch) mean / rstd over 4096 pixels of (a + b), f16 split-K partials
// ---------------------------------------------------------------------------
__global__ __launch_bounds__(256) void reduce_mv2(const short* __restrict__ xa,
                                                  const short* __restrict__ xb,
                                                  float* __restrict__ mr) {
  int bc = blockIdx.x, t = threadIdx.x;
  const short8* ap = (const short8*)(xa + ((size_t)bc << 12));
  const short8* bp = (const short8*)(xb + ((size_t)bc << 12));
  float s = 0.f, s2 = 0.f;
  for (int i = t; i < 512; i += 256) {
    short8 va = ap[i], vb = bp[i];
#pragma unroll
    for (int j = 0; j < 8; ++j) {
      float f = h2f(va[j]) + h2f(vb[j]);
      s += f;
      s2 += f * f;
    }
  }
#pragma unroll
  for (int off = 32; off; off >>= 1) {
    s += __shfl_down(s, off);
    s2 += __shfl_down(s2, off);
  }
  __shared__ float ls[4], ls2[4];
  int wid = t >> 6, lane = t & 63;
  if (!lane) { ls[wid] = s; ls2[wid] = s2; }
  __syncthreads();
  if (!t) {
    s = ls[0] + ls[1] + ls[2] + ls[3];
    s2 = ls2[0] + ls2[1] + ls2[2] + ls2[3];
    float m = s * (1.f / 4096.f);
    float var = s2 * (1.f / 4096.f) - m * m;
    mr[2 * bc] = m;
    mr[2 * bc + 1] = rsqrtf(fmaxf(var, 0.f) + IN_EPS);
  }
}

// ---------------------------------------------------------------------------
// out = relu(((a+b) - mean)*rstd), f16 partials in, f32 out
// grid: 2048 x 256 -> 524,288 threads x 8 elems = 4,194,304 (full output)
// ---------------------------------------------------------------------------
__global__ __launch_bounds__(256) void finalize2(const short* __restrict__ ya,
                                                 const short* __restrict__ yb,
                                                 const float* __restrict__ mr,
                                                 float* __restrict__ out) {
  int i = blockIdx.x * 256 + threadIdx.x;
  int bc = i >> 9;
  float m = mr[2 * bc], r = mr[2 * bc + 1];
  short8 va = ((const short8*)ya)[i];
  short8 vb = ((const short8*)yb)[i];
  float4 o0, o1;
#pragma unroll
  for (int j = 0; j < 8; ++j) {
    float f = fmaxf((h2f(va[j]) + h2f(vb[j]) - m) * r, 0.f);
    if (j < 4) ((float*)&o0)[j] = f;
    else ((float*)&o1)[j - 4] = f;
  }
  ((float4*)out)[2 * i] = o0;
  ((float4*)out)[2 * i + 1] = o1;
}

extern "C" void kernel_launch(void* const* d_in, const int* in_sizes, int n_in,
                              void* d_out, int out_size, void* d_ws,
                              size_t ws_size, hipStream_t stream) {
  (void)in_sizes; (void)n_in; (void)out_size; (void)ws_size;
  const float* feat  = (const float*)d_in[0];
  const float* guide = (const float*)d_in[1];
  const float* pac_w = (const float*)d_in[2];
  const float* dec_w = (const float*)d_in[3];
  // d_in[4] (dec_b): per-channel constant bias cancels in InstanceNorm mean.
  float* out = (float*)d_out;
  char* ws = (char*)d_ws;

  float* kernbuf = (float*)(ws);                 // 8*9*4096*4   = 0x120000
  short* Ws1     = (short*)(ws + 0x120000);      // 2*36*8192*2  = 0x120000
  short* Ws2     = (short*)(ws + 0x240000);      // 1*36*8192*2  = 0x090000
  float* mr1     = (float*)(ws + 0x2D0000);      // 2048*2*4
  float* mr2     = (float*)(ws + 0x2D4000);      // 1024*2*4
  short* pac     = (short*)(ws + 0x300000);      // 8*256*4096*2 = 0x1000000
  short* ybufA   = (short*)(ws + 0x1300000);     // 8*128*4096*2 = 0x800000
  short* ybufB   = (short*)(ws + 0x1B00000);     // 8*128*4096*2 = 0x800000

  wconv_k<<<(256 * 2304 + 255) / 256, 256, 0, stream>>>(pac_w, Ws1, 256);
  wconv_k<<<(128 * 2304 + 255) / 256, 256, 0, stream>>>(dec_w, Ws2, 128);
  kern_k<<<dim3(64, 8), 256, 0, stream>>>(guide, kernbuf);

  gemm_conv<256, true, false, false, false><<<dim3(32, 2, 8), 512, 0, stream>>>(
      Ws1, feat, kernbuf, nullptr, pac, nullptr);
  reduce_mv<<<8 * 256, 256, 0, stream>>>(pac, mr1);
  gemm_conv<128, false, true, true, true><<<dim3(32, 2, 8), 512, 0, stream>>>(
      Ws2, pac, nullptr, mr1, ybufA, ybufB);
  reduce_mv2<<<8 * 128, 256, 0, stream>>>(ybufA, ybufB, mr2);
  finalize2<<<2048, 256, 0, stream>>>(ybufA, ybufB, mr2, out);
}

// Round 15
// 121.685 us; speedup vs baseline: 1.6226x; 1.1197x over previous
//
#include <hip/hip_runtime.h>
#include <hip/hip_bf16.h>
#include <hip/hip_fp16.h>

#define IN_EPS 1e-5f

typedef __attribute__((ext_vector_type(8))) short short8;
typedef __attribute__((ext_vector_type(4))) float f32x4;
typedef _Float16 half8 __attribute__((ext_vector_type(8)));

__device__ __forceinline__ short f2h(float f) {
  __half h = __float2half(f);
  return *(short*)&h;
}
__device__ __forceinline__ float h2f(short s) {
  __half h = *(__half*)&s;
  return __half2float(h);
}

// packed multiply: all 8 f16 lanes of v times the f16 broadcast pair in kbits
__device__ __forceinline__ short8 pkmul(short8 v, unsigned kbits) {
  union { short8 s; unsigned u[4]; } x;
  x.s = v;
  __half2 k = *(__half2*)&kbits;
#pragma unroll
  for (int i = 0; i < 4; ++i) {
    __half2 h = *(__half2*)&x.u[i];
    h = __hmul2(h, k);
    x.u[i] = *(unsigned*)&h;
  }
  return x.s;
}

// ---------------------------------------------------------------------------
// Weight conversion: f32 [O][C][3][3] -> f16 swizzled panel image.
// Panel p = mblk*36 + cb*9 + tap holds [o_local 128][c_local 64], elem at
//   (p<<13) + (ol<<6) + (cl ^ ((ol&7)<<3))
// ---------------------------------------------------------------------------
__global__ void wconv_k(const float* __restrict__ src, short* __restrict__ dst,
                        int O) {
  int idx = blockIdx.x * 256 + threadIdx.x;
  if (idx >= O * 2304) return;
  int o = idx / 2304;
  int r = idx - o * 2304;
  int c = r / 9;
  int k = r - c * 9;
  int mblk = o >> 7, ol = o & 127, cb = c >> 6, cl = c & 63;
  dst[(((size_t)(mblk * 36 + cb * 9 + k)) << 13) + (ol << 6) + (cl ^ ((ol & 7) << 3))]
      = f2h(src[idx]);
}

// ---------------------------------------------------------------------------
// Adaptive Gaussian kernel: kern[b][k][h][w] = exp(-0.5 * sum_c dg^2)
// 1024 thr: 64 cols x 16 channel-groups (16 ch each, 16-iter chain).
// h-tile = 2: block loads 4 guide rows/channel instead of 6 (2/3 traffic).
// lane == image col; neighbors via shfl; no barriers in the channel loop.
// ---------------------------------------------------------------------------
__global__ __launch_bounds__(1024) void kern_k(const float* __restrict__ g,
                                               float* __restrict__ kern) {
  int hb = blockIdx.x, b = blockIdx.y;
  int h0 = hb * 2;
  int t = threadIdx.x, w = t & 63, cg = t >> 6;   // cg 0..15
  float acc[2][9];
#pragma unroll
  for (int hh = 0; hh < 2; ++hh)
#pragma unroll
    for (int k = 0; k < 9; ++k) acc[hh][k] = 0.f;
  const float* base = g + (((size_t)b * 256 + (cg << 4)) << 12) + (h0 << 6) + w;
#pragma unroll 4
  for (int cc = 0; cc < 16; ++cc) {
    const float* gp = base + ((size_t)cc << 12);
    float r0 = (h0 > 0) ? gp[-64] : 0.f;     // h0-1
    float r1 = gp[0];                         // h0
    float r2 = gp[64];                        // h0+1  (h0<=62 always)
    float r3 = (h0 < 62) ? gp[128] : 0.f;     // h0+2
    float rows[4] = {r0, r1, r2, r3};
    float ls[4], rs[4];
#pragma unroll
    for (int i = 0; i < 4; ++i) {
      float v = rows[i];
      float l = __shfl_up(v, 1);
      float r = __shfl_down(v, 1);
      if (w == 0) l = 0.f;
      if (w == 63) r = 0.f;
      ls[i] = l;
      rs[i] = r;
    }
#pragma unroll
    for (int hh = 0; hh < 2; ++hh) {
      float ctr = rows[hh + 1];
#pragma unroll
      for (int i = 0; i < 3; ++i) {
        float dl = ls[hh + i] - ctr, dm = rows[hh + i] - ctr, dr = rs[hh + i] - ctr;
        acc[hh][i * 3 + 0] += dl * dl;
        acc[hh][i * 3 + 1] += dm * dm;
        acc[hh][i * 3 + 2] += dr * dr;
      }
    }
  }
  __shared__ float red[16][2][9][64];
#pragma unroll
  for (int hh = 0; hh < 2; ++hh)
#pragma unroll
    for (int k = 0; k < 9; ++k) red[cg][hh][k][w] = acc[hh][k];
  __syncthreads();
  for (int idx = t; idx < 1152; idx += 1024) {
    int hh = idx / 576, rem = idx - hh * 576;
    int k = rem >> 6, w2 = rem & 63;
    float s = 0.f;
#pragma unroll
    for (int gi = 0; gi < 16; ++gi) s += red[gi][hh][k][w2];
    kern[(((size_t)b * 9 + k) << 12) + ((h0 + hh) << 6) + w2] = expf(-0.5f * s);
  }
}

// ---------------------------------------------------------------------------
// Implicit-GEMM conv with tap-reuse (R12 structure, f16 in/out). BM=128,
// BN=128, 512 thr / 8 waves (2M x 4N, wave tile 64x32). K = ncb cblk x 9 taps.
// A: LDS dbuf, reg-staged; ONE barrier per non-boundary step.
// B: halo [4 rows][64 cols][64 ch] f16, staged once per c-block; T14
//    issue-early for BOTH GEMMs (mreg loaded inside writeB, only breg held).
// X input: f32 (GEMM1/feat) or f16 (GEMM2/pac) via XF16.
// Output: f16 (pac or split-K partials).
// GEMM1 (USE_KERN): kern folded into B fragment via v_pk_mul_f16.
// GEMM2 (USE_NORM, KSPLIT): norm+relu fused into staging; K split across
//    blockIdx.y; f16 partials to outA / outB.
// ---------------------------------------------------------------------------
template <int MTOT, bool USE_KERN, bool USE_NORM, bool KSPLIT, bool XF16>
__global__ __launch_bounds__(512, 4) void gemm_conv(
    const short* __restrict__ Wimg, const void* __restrict__ Xv,
    const float* __restrict__ Kf, const float* __restrict__ MRin,
    short* __restrict__ outA, short* __restrict__ outB) {
  __shared__ short ldsA[2][8192];  // [o 128][c 64] swizzled, dbuf, 32KB
  __shared__ short ldsB[16384];    // [r 4][col 64][c 64] swizzled, 32KB
  __shared__ short ldsS[512];      // side halo cols (-1,64): zeros, 1KB
  __shared__ short klds[USE_KERN ? 1152 : 1];  // kern f16 [9][128]

  const int t = threadIdx.x;
  const int nblk = blockIdx.x, b = blockIdx.z;
  const int mblk = KSPLIT ? 0 : blockIdx.y;
  const int cb0 = KSPLIT ? (int)blockIdx.y * 2 : 0;
  const int ncb = KSPLIT ? 2 : 4;
  short* __restrict__ outp = (KSPLIT && blockIdx.y) ? outB : outA;
  const int h0 = nblk * 2;
  const int lane = t & 63, wid = t >> 6;
  const int wr = wid >> 2, wc = wid & 3;
  const int fr = lane & 15, kg = (lane >> 4) << 3;
  const int scol = t & 63, c8 = (t >> 6) << 3;   // B staging: col, 8-ch base

  f32x4 acc[4][2];
#pragma unroll
  for (int i = 0; i < 4; ++i)
#pragma unroll
    for (int j = 0; j < 2; ++j) acc[i][j] = {0.f, 0.f, 0.f, 0.f};

  float breg[4][8];

  auto loadA = [&](int pan, short8* ar) {
    const short* src =
        Wimg + (((size_t)(mblk * 36 + cb0 * 9 + pan)) << 13) + (t << 3);
    ar[0] = *(const short8*)(src);
    ar[1] = *(const short8*)(src + 4096);
  };
  auto writeA = [&](const short8* ar, int buf) {
    *(short8*)&ldsA[buf][t << 3] = ar[0];
    *(short8*)&ldsA[buf][4096 + (t << 3)] = ar[1];
  };
  auto loadBregs = [&](int cbrel) {
    int c0 = ((cb0 + cbrel) << 6) + c8;
    size_t off = (((size_t)b * 256 + c0) << 12) + scol;
#pragma unroll
    for (int r = 0; r < 4; ++r) {
      int hr = h0 - 1 + r;
      bool okr = (unsigned)hr < 64u;
#pragma unroll
      for (int i = 0; i < 8; ++i) {
        if (XF16) {
          const short* src = (const short*)Xv + off + (hr << 6);
          breg[r][i] = okr ? h2f(src[(size_t)i << 12]) : 0.f;
        } else {
          const float* src = (const float*)Xv + off + (hr << 6);
          breg[r][i] = okr ? src[(size_t)i << 12] : 0.f;
        }
      }
    }
  };
  auto writeB = [&](int cbrel) {
    float2 mreg[8];
    if (USE_NORM) {
      int c0 = ((cb0 + cbrel) << 6) + c8;
#pragma unroll
      for (int i = 0; i < 8; ++i)
        mreg[i] = ((const float2*)MRin)[b * 256 + c0 + i];
    }
#pragma unroll
    for (int r = 0; r < 4; ++r) {
      short8 pk;
#pragma unroll
      for (int i = 0; i < 8; ++i) {
        float x = breg[r][i];
        if (USE_NORM) x = fmaxf((x - mreg[i].x) * mreg[i].y, 0.f);
        pk[i] = f2h(x);
      }
      *(short8*)&ldsB[(((r << 6) + scol) << 6) + (c8 ^ ((scol & 7) << 3))] = pk;
    }
  };
  auto computeTap = [&](int tap, int buf) {
    const int di = tap / 3 - 1, dj = tap % 3 - 1;
    unsigned kq2[2];
    if (USE_KERN) {
#pragma unroll
      for (int nf = 0; nf < 2; ++nf) {
        short kh = klds[tap * 128 + (wc << 5) + (nf << 4) + fr];
        __half h = *(__half*)&kh;
        __half2 h2 = __half2half2(h);
        kq2[nf] = *(unsigned*)&h2;
      }
    }
#pragma unroll
    for (int ks = 0; ks < 2; ++ks) {
      int kb = (ks << 5) + kg;
      short8 a4[4], b2[2];
#pragma unroll
      for (int mf = 0; mf < 4; ++mf) {
        int rr = (wr << 6) + (mf << 4) + fr;
        a4[mf] = *(const short8*)&ldsA[buf][(rr << 6) + (kb ^ ((rr & 7) << 3))];
      }
#pragma unroll
      for (int nf = 0; nf < 2; ++nf) {
        int px = (wc << 5) + (nf << 4) + fr;
        int rr2 = (px >> 6) + di + 1;
        int wcol = (px & 63) + dj;
        int kbs = kb ^ ((wcol & 7) << 3);
        const short* pm = &ldsB[(((rr2 << 6) + wcol) << 6) + kbs];
        const short* ps = &ldsS[(((rr2 << 1) + (wcol == 64)) << 6) + kbs];
        short8 bb = *(const short8*)(((unsigned)wcol < 64u) ? pm : ps);
        if (USE_KERN) bb = pkmul(bb, kq2[nf]);
        b2[nf] = bb;
      }
      __builtin_amdgcn_s_setprio(1);
#pragma unroll
      for (int mf = 0; mf < 4; ++mf)
#pragma unroll
        for (int nf = 0; nf < 2; ++nf)
          acc[mf][nf] = __builtin_amdgcn_mfma_f32_16x16x32_f16(
              *(half8*)&a4[mf], *(half8*)&b2[nf], acc[mf][nf], 0, 0, 0);
      __builtin_amdgcn_s_setprio(0);
    }
  };

  // ---- prologue ----
  if (t < 64) {
    short8 z = {0, 0, 0, 0, 0, 0, 0, 0};
    *(short8*)&ldsS[t << 3] = z;
  }
  if (USE_KERN) {
    for (int idx = t; idx < 1152; idx += 512) {
      int tap = idx >> 7, px = idx & 127;
      klds[idx] = f2h(Kf[(((size_t)b * 9 + tap) << 12) +
                         ((h0 + (px >> 6)) << 6) + (px & 63)]);
    }
  }
  {
    short8 ar[2];
    loadA(0, ar);
    loadBregs(0);
    writeA(ar, 0);
    writeB(0);
  }
  __syncthreads();

  // ---- main loop: ncb c-blocks x 9 taps; 1 barrier per interior step ----
  const int nt = ncb * 9;
  int tap = 0, cbrel = 0;
  for (int pan = 0; pan < nt; ++pan) {
    int buf = pan & 1;
    bool more = (pan + 1) < nt;
    bool lastTap = (tap == 8);
    short8 ar[2];
    if (more) loadA(pan + 1, ar);                // overlaps compute
    if (more && lastTap) loadBregs(cbrel + 1);   // T14 issue-early (both GEMMs)
    computeTap(tap, buf);
    if (more && lastTap) {
      __syncthreads();                 // B readers done
      writeB(cbrel + 1);               // mreg loaded inside (norm path)
      writeA(ar, buf ^ 1);
      __syncthreads();                 // publish A+B
    } else if (more) {
      writeA(ar, buf ^ 1);             // idle buffer: no pre-write barrier
      __syncthreads();                 // publish A
    }
    if (++tap == 9) { tap = 0; ++cbrel; }
  }

  // ---- epilogue: f16 out ----
  const int row4 = (lane >> 4) << 2;
#pragma unroll
  for (int mf = 0; mf < 4; ++mf) {
    int o = (mblk << 7) + (wr << 6) + (mf << 4) + row4;
    size_t ob = (((size_t)b * MTOT + o) << 12) + (nblk << 7) + (wc << 5) + fr;
#pragma unroll
    for (int nf = 0; nf < 2; ++nf) {
      f32x4 v = acc[mf][nf];
      size_t oo = ob + (nf << 4);
      outp[oo] = f2h(v[0]);
      outp[oo + 4096] = f2h(v[1]);
      outp[oo + 8192] = f2h(v[2]);
      outp[oo + 12288] = f2h(v[3]);
    }
  }
}

// ---------------------------------------------------------------------------
// per-(b,ch) mean / rstd over 4096 pixels of f16 input
// ---------------------------------------------------------------------------
__global__ __launch_bounds__(256) void reduce_mv(const short* __restrict__ x,
                                                 float* __restrict__ mr) {
  int bc = blockIdx.x, t = threadIdx.x;
  const short8* xp = (const short8*)(x + ((size_t)bc << 12));
  float s = 0.f, s2 = 0.f;
  for (int i = t; i < 512; i += 256) {
    short8 v = xp[i];
#pragma unroll
    for (int j = 0; j < 8; ++j) {
      float f = h2f(v[j]);
      s += f;
      s2 += f * f;
    }
  }
#pragma unroll
  for (int off = 32; off; off >>= 1) {
    s += __shfl_down(s, off);
    s2 += __shfl_down(s2, off);
  }
  __shared__ float ls[4], ls2[4];
  int wid = t >> 6, lane = t & 63;
  if (!lane) { ls[wid] = s; ls2[wid] = s2; }
  __syncthreads();
  if (!t) {
    s = ls[0] + ls[1] + ls[2] + ls[3];
    s2 = ls2[0] + ls2[1] + ls2[2] + ls2[3];
    float m = s * (1.f / 4096.f);
    float var = s2 * (1.f / 4096.f) - m * m;
    mr[2 * bc] = m;
    mr[2 * bc + 1] = rsqrtf(fmaxf(var, 0.f) + IN_EPS);
  }
}

// ---------------------------------------------------------------------------
// per-(b,ch) mean / rstd over 4096 pixels of (a + b), f16 split-K partials
// ---------------------------------------------------------------------------
__global__ __launch_bounds__(256) void reduce_mv2(const short* __restrict__ xa,
                                                  const short* __restrict__ xb,
                                                  float* __restrict__ mr) {
  int bc = blockIdx.x, t = threadIdx.x;
  const short8* ap = (const short8*)(xa + ((size_t)bc << 12));
  const short8* bp = (const short8*)(xb + ((size_t)bc << 12));
  float s = 0.f, s2 = 0.f;
  for (int i = t; i < 512; i += 256) {
    short8 va = ap[i], vb = bp[i];
#pragma unroll
    for (int j = 0; j < 8; ++j) {
      float f = h2f(va[j]) + h2f(vb[j]);
      s += f;
      s2 += f * f;
    }
  }
#pragma unroll
  for (int off = 32; off; off >>= 1) {
    s += __shfl_down(s, off);
    s2 += __shfl_down(s2, off);
  }
  __shared__ float ls[4], ls2[4];
  int wid = t >> 6, lane = t & 63;
  if (!lane) { ls[wid] = s; ls2[wid] = s2; }
  __syncthreads();
  if (!t) {
    s = ls[0] + ls[1] + ls[2] + ls[3];
    s2 = ls2[0] + ls2[1] + ls2[2] + ls2[3];
    float m = s * (1.f / 4096.f);
    float var = s2 * (1.f / 4096.f) - m * m;
    mr[2 * bc] = m;
    mr[2 * bc + 1] = rsqrtf(fmaxf(var, 0.f) + IN_EPS);
  }
}

// ---------------------------------------------------------------------------
// out = relu(((a+b) - mean)*rstd), f16 partials in, f32 out
// grid: 2048 x 256 -> 524,288 threads x 8 elems = 4,194,304 (full output)
// ---------------------------------------------------------------------------
__global__ __launch_bounds__(256) void finalize2(const short* __restrict__ ya,
                                                 const short* __restrict__ yb,
                                                 const float* __restrict__ mr,
                                                 float* __restrict__ out) {
  int i = blockIdx.x * 256 + threadIdx.x;
  int bc = i >> 9;
  float m = mr[2 * bc], r = mr[2 * bc + 1];
  short8 va = ((const short8*)ya)[i];
  short8 vb = ((const short8*)yb)[i];
  float4 o0, o1;
#pragma unroll
  for (int j = 0; j < 8; ++j) {
    float f = fmaxf((h2f(va[j]) + h2f(vb[j]) - m) * r, 0.f);
    if (j < 4) ((float*)&o0)[j] = f;
    else ((float*)&o1)[j - 4] = f;
  }
  ((float4*)out)[2 * i] = o0;
  ((float4*)out)[2 * i + 1] = o1;
}

extern "C" void kernel_launch(void* const* d_in, const int* in_sizes, int n_in,
                              void* d_out, int out_size, void* d_ws,
                              size_t ws_size, hipStream_t stream) {
  (void)in_sizes; (void)n_in; (void)out_size; (void)ws_size;
  const float* feat  = (const float*)d_in[0];
  const float* guide = (const float*)d_in[1];
  const float* pac_w = (const float*)d_in[2];
  const float* dec_w = (const float*)d_in[3];
  // d_in[4] (dec_b): per-channel constant bias cancels in InstanceNorm mean.
  float* out = (float*)d_out;
  char* ws = (char*)d_ws;

  float* kernbuf = (float*)(ws);                 // 8*9*4096*4   = 0x120000
  short* Ws1     = (short*)(ws + 0x120000);      // 2*36*8192*2  = 0x120000
  short* Ws2     = (short*)(ws + 0x240000);      // 1*36*8192*2  = 0x090000
  float* mr1     = (float*)(ws + 0x2D0000);      // 2048*2*4
  float* mr2     = (float*)(ws + 0x2D4000);      // 1024*2*4
  short* pac     = (short*)(ws + 0x300000);      // 8*256*4096*2 = 0x1000000
  short* ybufA   = (short*)(ws + 0x1300000);     // 8*128*4096*2 = 0x800000
  short* ybufB   = (short*)(ws + 0x1B00000);     // 8*128*4096*2 = 0x800000

  wconv_k<<<(256 * 2304 + 255) / 256, 256, 0, stream>>>(pac_w, Ws1, 256);
  wconv_k<<<(128 * 2304 + 255) / 256, 256, 0, stream>>>(dec_w, Ws2, 128);
  kern_k<<<dim3(32, 8), 1024, 0, stream>>>(guide, kernbuf);

  gemm_conv<256, true, false, false, false><<<dim3(32, 2, 8), 512, 0, stream>>>(
      Ws1, feat, kernbuf, nullptr, pac, nullptr);
  reduce_mv<<<8 * 256, 256, 0, stream>>>(pac, mr1);
  gemm_conv<128, false, true, true, true><<<dim3(32, 2, 8), 512, 0, stream>>>(
      Ws2, pac, nullptr, mr1, ybufA, ybufB);
  reduce_mv2<<<8 * 128, 256, 0, stream>>>(ybufA, ybufB, mr2);
  finalize2<<<2048, 256, 0, stream>>>(ybufA, ybufB, mr2, out);
}